// Round 13
// baseline (106.553 us; speedup 1.0000x reference)
//
#include <hip/hip_runtime.h>
#include <hip/hip_bf16.h>
#include <math.h>

#define EPS 1e-6f
#define NSINK 1024
#define NSRC 4096
#define DIM 512
#define NH 8
#define HD 64
#define BATCH 2
// fold (d^-0.5 = 1/8) * log2(e) into q so sim exp is a single exp2
#define QSCALE 0.18033688011112042f

#if __has_builtin(__builtin_amdgcn_permlane32_swap) && __has_builtin(__builtin_amdgcn_permlane16_swap)
#define HAVE_PERMLANE 1
#else
#define HAVE_PERMLANE 0
#endif

typedef unsigned short u16;
typedef __attribute__((ext_vector_type(8))) short short8;
typedef __attribute__((ext_vector_type(4))) float f32x4;

__device__ inline float fast_exp2(float x) {
#if __has_builtin(__builtin_amdgcn_exp2f)
    return __builtin_amdgcn_exp2f(x);
#else
    return exp2f(x);
#endif
}
__device__ inline float fast_rcp(float x) {
#if __has_builtin(__builtin_amdgcn_rcpf)
    return __builtin_amdgcn_rcpf(x);
#else
    return 1.0f / x;
#endif
}
__device__ inline u16 f2bf(float x) {
    union { float f; unsigned u; } v; v.f = x;
    unsigned r = v.u + 0x7fffu + ((v.u >> 16) & 1u);
    return (u16)(r >> 16);
}
__device__ inline float bf2f(u16 h) {
    union { unsigned u; float f; } v; v.u = ((unsigned)h) << 16;
    return v.f;
}
// pack 2 f32 -> 2 bf16 (RTNE) in one u32; lowers to v_cvt_pk_bf16_f32
__device__ inline unsigned pk_bf16(float a, float b) {
    union { __hip_bfloat162 h; unsigned u; } v;
    v.h = __float22bfloat162_rn(make_float2(a, b));
    return v.u;
}
__device__ inline f32x4 mfma16(short8 a, short8 b, f32x4 c) {
    return __builtin_amdgcn_mfma_f32_16x16x32_bf16(a, b, c, 0, 0, 0);
}
// direct-from-global fragment loader
__device__ inline short8 ldfrag(const u16* base, int stride, int lane) {
    return *(const short8*)(base + (size_t)(lane & 15) * stride + ((lane >> 4) << 3));
}

// async global->LDS, 16B per lane
__device__ inline void gld16(const u16* g, u16* l) {
    __builtin_amdgcn_global_load_lds(
        (const __attribute__((address_space(1))) unsigned*)g,
        (__attribute__((address_space(3))) unsigned*)l, 16, 0, 0);
}

// stage a [TM][64] bf16 tile from gsrc (row-major, stride K);
// LDS linear dest; global source inverse-swizzled (c ^= m&7).
template<int TM>
__device__ inline void stage_tile(u16* lds, const u16* gsrc, int K, int t) {
    #pragma unroll
    for (int it = 0; it < TM / 32; ++it) {
        int m = it * 32 + (t >> 3);
        int c = (t & 7) ^ (m & 7);
        gld16(gsrc + (size_t)m * K + c * 8,
              lds + it * 2048 + (t >> 6) * 512);
    }
}
// swizzled fragment read
__device__ inline short8 rdfrag(const u16* tile, int fbase, int cbase, int lane) {
    int m = fbase + (lane & 15);
    int c = (cbase + (lane >> 4)) ^ (m & 7);
    return *(const short8*)(tile + (size_t)m * 64 + c * 8);
}

#if HAVE_PERMLANE
// Build the PV A-fragment in-register from swapped-QK scores (already scaled).
__device__ inline short8 pa_frag(const f32x4 sA, const f32x4 sB) {
    unsigned A0 = pk_bf16(sA[0], sA[1]);
    unsigned A1 = pk_bf16(sA[2], sA[3]);
    unsigned B0 = pk_bf16(sB[0], sB[1]);
    unsigned B1 = pk_bf16(sB[2], sB[3]);
    auto c0 = __builtin_amdgcn_permlane32_swap(A0, B0, false, false);
    auto c1 = __builtin_amdgcn_permlane32_swap(A1, B1, false, false);
    auto d0 = __builtin_amdgcn_permlane16_swap(c0[0], c0[1], false, false);
    auto d1 = __builtin_amdgcn_permlane16_swap(c1[0], c1[1], false, false);
    union { unsigned u[4]; short8 s8; } r;
    r.u[0] = d0[0]; r.u[1] = d1[0]; r.u[2] = d0[1]; r.u[3] = d1[1];
    return r.s8;
}
#endif

// ---------------- prep: fused LayerNorm (both inputs) + weight transposes ----------------
__global__ __launch_bounds__(256) void prep(
    const float* __restrict__ sink, const float* __restrict__ source,
    const float* __restrict__ gs, const float* __restrict__ bs,
    const float* __restrict__ gc, const float* __restrict__ bc,
    const float* __restrict__ Wq, const float* __restrict__ Wkv,
    const float* __restrict__ Wo,
    u16* __restrict__ sh, u16* __restrict__ ch,
    u16* __restrict__ wqT, u16* __restrict__ wkvT, u16* __restrict__ woT)
{
    int row = blockIdx.x;
    int t = threadIdx.x;
    if (row >= BATCH * (NSINK + NSRC)) {   // weight transpose blocks
        int n = row - BATCH * (NSINK + NSRC);
        const float* W; u16* T; int N; int nn;
        if (n < 512)       { W = Wq;  T = wqT;  N = 512;  nn = n; }
        else if (n < 1536) { W = Wkv; T = wkvT; N = 1024; nn = n - 512; }
        else               { W = Wo;  T = woT;  N = 512;  nn = n - 1536; }
        for (int k = t; k < 512; k += 256)
            T[(size_t)nn * 512 + k] = f2bf(W[(size_t)k * N + nn]);
        return;
    }
    const float* xr; const float* g; const float* be; u16* y;
    if (row < BATCH * NSINK) {
        xr = sink + (size_t)row * DIM; g = gs; be = bs; y = sh + (size_t)row * DIM;
    } else {
        int rr = row - BATCH * NSINK;
        xr = source + (size_t)rr * DIM; g = gc; be = bc; y = ch + (size_t)rr * DIM;
    }
    float v0 = xr[t], v1 = xr[t + 256];
    float s = v0 + v1, sq = v0 * v0 + v1 * v1;
    #pragma unroll
    for (int off = 32; off > 0; off >>= 1) {
        s  += __shfl_down(s, off, 64);
        sq += __shfl_down(sq, off, 64);
    }
    __shared__ float rsm[4], rq[4];
    int wave = t >> 6;
    if ((t & 63) == 0) { rsm[wave] = s; rq[wave] = sq; }
    __syncthreads();
    s  = rsm[0] + rsm[1] + rsm[2] + rsm[3];
    sq = rq[0] + rq[1] + rq[2] + rq[3];
    float mu = s * (1.0f / DIM);
    float var = sq * (1.0f / DIM) - mu * mu;
    float a = var + EPS;
    float r = rsqrtf(a);
    r = r * (1.5f - 0.5f * a * r * r);
    y[t]       = f2bf((v0 - mu) * r * g[t] + be[t]);
    y[t + 256] = f2bf((v1 - mu) * r * g[t + 256] + be[t + 256]);
}

// ---------------- 1-term 2-phase LDS-dbuf MFMA GEMM: C = A @ BT^T + bias ----------------
// MODE 0: C fp32 row-major. MODE 1: q bf16 [bh][i][d] * QSCALE.
// MODE 2: n<512 -> k bf16 [bh][j][d]; n>=512 -> vT bf16 [bh*64+d][j].
// SWZ: 1-D grid, XCD-affine decode
template<int MODE, int TM, int TN, int SWZ>
__global__ __launch_bounds__(256) void gemm1(
    const u16* __restrict__ A, const u16* __restrict__ BT,
    const float* __restrict__ bias, int K,
    float* __restrict__ cf, u16* __restrict__ o1, u16* __restrict__ o2)
{
    constexpr int FM = TM / 32, FN = TN / 32;
    __shared__ u16 As[2][TM * 64];
    __shared__ u16 Bs[2][TN * 64];
    int t = threadIdx.x;
    int wave = t >> 6, lane = t & 63;
    int wr = wave >> 1, wc = wave & 1;
    int m0, n0;
    if constexpr (SWZ) {
        int id = blockIdx.x;            // 512 blocks: 64 m-tiles x 8 n-tiles
        int slot = id >> 3;             // 0..63
        m0 = ((id & 7) * 8 + (slot & 7)) * TM;
        n0 = (slot >> 3) * TN;
    } else {
        m0 = blockIdx.y * TM;
        n0 = blockIdx.x * TN;
    }

    f32x4 acc[FM][FN] = {};
    stage_tile<TM>(As[0], A + (size_t)m0 * K, K, t);
    stage_tile<TN>(Bs[0], BT + (size_t)n0 * K, K, t);
    __syncthreads();
    int nt = K >> 6;
    int cur = 0;
    for (int kt = 0; kt < nt; ++kt) {
        if (kt + 1 < nt) {
            stage_tile<TM>(As[cur ^ 1], A + (size_t)m0 * K + (kt + 1) * 64, K, t);
            stage_tile<TN>(Bs[cur ^ 1], BT + (size_t)n0 * K + (kt + 1) * 64, K, t);
        }
        #pragma unroll
        for (int kk = 0; kk < 2; ++kk) {
            short8 af[FM], bf[FN];
            #pragma unroll
            for (int f = 0; f < FM; ++f)
                af[f] = rdfrag(As[cur], wr * (TM / 2) + f * 16, kk * 4, lane);
            #pragma unroll
            for (int f = 0; f < FN; ++f)
                bf[f] = rdfrag(Bs[cur], wc * (TN / 2) + f * 16, kk * 4, lane);
            #pragma unroll
            for (int i = 0; i < FM; ++i)
                #pragma unroll
                for (int j = 0; j < FN; ++j)
                    acc[i][j] = mfma16(af[i], bf[j], acc[i][j]);
        }
        __syncthreads();
        cur ^= 1;
    }

    #pragma unroll
    for (int i = 0; i < FM; ++i)
        #pragma unroll
        for (int j = 0; j < FN; ++j)
            #pragma unroll
            for (int r = 0; r < 4; ++r) {
                int m = m0 + wr * (TM / 2) + i * 16 + (lane >> 4) * 4 + r;
                int n = n0 + wc * (TN / 2) + j * 16 + (lane & 15);
                float v = acc[i][j][r] + bias[n];
                if (MODE == 0) {
                    cf[(size_t)m * DIM + n] = v;
                } else if (MODE == 1) {
                    int b = m >> 10, ii = m & 1023;
                    int h = n >> 6, d = n & 63;
                    o1[((size_t)(b * NH + h) * NSINK + ii) * HD + d] = f2bf(v * QSCALE);
                } else {
                    int b = m >> 12, jj = m & 4095;
                    if (n < DIM) {
                        int h = n >> 6, d = n & 63;
                        o1[((size_t)(b * NH + h) * NSRC + jj) * HD + d] = f2bf(v);
                    } else {
                        int nn = n - DIM;
                        int h = nn >> 6, d = nn & 63;
                        o2[((size_t)(b * NH + h) * HD + d) * NSRC + jj] = f2bf(v);
                    }
                }
            }
}

// ---------------- pass A: colsum_part[ic][bh][j] = sum_{i chunk} exp2(q.k) ----------------
__global__ __launch_bounds__(256, 4) void pass_a(const u16* __restrict__ q,
    const u16* __restrict__ k, float* __restrict__ part)
{
    int id = blockIdx.x;
    int slot = id >> 3;
    int bh = (id & 7) + 8 * (slot >> 6);
    int rem = slot & 63;
    int ic = rem >> 4;
    int t = threadIdx.x, wave = t >> 6, lane = t & 63;
    int j0 = (rem & 15) * 256 + wave * 64;
    const u16* qb = q + (size_t)bh * NSINK * HD;
    const u16* kb = k + (size_t)bh * NSRC * HD;

    __shared__ u16 Qs[2][64 * 64];

    short8 kf[4][2];
    #pragma unroll
    for (int jf = 0; jf < 4; ++jf)
        #pragma unroll
        for (int kc = 0; kc < 2; ++kc)
            kf[jf][kc] = ldfrag(kb + (size_t)(j0 + jf * 16) * HD + kc * 32, HD, lane);

    float csum[4] = {};
    stage_tile<64>(Qs[0], qb + (size_t)(ic * 256) * HD, HD, t);
    __syncthreads();
    int cur = 0;
    for (int ii = 0; ii < 4; ++ii) {
        if (ii + 1 < 4)
            stage_tile<64>(Qs[cur ^ 1], qb + (size_t)(ic * 256 + (ii + 1) * 64) * HD, HD, t);
        #pragma unroll
        for (int f = 0; f < 4; ++f) {
            short8 q0 = rdfrag(Qs[cur], f * 16, 0, lane);
            short8 q1 = rdfrag(Qs[cur], f * 16, 4, lane);
            f32x4 s[4] = {};
            #pragma unroll
            for (int jf = 0; jf < 4; ++jf) s[jf] = mfma16(q0, kf[jf][0], s[jf]);
            #pragma unroll
            for (int jf = 0; jf < 4; ++jf) s[jf] = mfma16(q1, kf[jf][1], s[jf]);
            #pragma unroll
            for (int jf = 0; jf < 4; ++jf)
                csum[jf] += fast_exp2(s[jf][0]) + fast_exp2(s[jf][1])
                          + fast_exp2(s[jf][2]) + fast_exp2(s[jf][3]);
        }
        __syncthreads();   // drains prefetch vmcnt; guards buffer reuse
        cur ^= 1;
    }
    #pragma unroll
    for (int jf = 0; jf < 4; ++jf) {
        csum[jf] += __shfl_xor(csum[jf], 16, 64);
        csum[jf] += __shfl_xor(csum[jf], 32, 64);
    }
    if (lane < 16)
        #pragma unroll
        for (int jf = 0; jf < 4; ++jf)
            part[((size_t)ic * BATCH * NH + bh) * NSRC + j0 + jf * 16 + lane] = csum[jf];
}

// ---------------- csred_vsum: rcs = 1/sum(parts) (blocks 0..255); vs = sum_j v (blocks 256..1279) ----------------
__global__ __launch_bounds__(256) void csred_vsum(const float* __restrict__ part,
    const u16* __restrict__ vTh, float* __restrict__ rcs, float* __restrict__ vs)
{
    int blk = blockIdx.x;
    if (blk < 256) {
        int x = blk * 256 + threadIdx.x;   // 16*4096 total
        const int S = BATCH * NH * NSRC;
        float cs = part[x] + part[x + S] + part[x + 2 * S] + part[x + 3 * S];
        rcs[x] = fast_rcp(cs);
        return;
    }
    int row = blk - 256;                   // 0..1023 = bh*64+d
    const u16* ph = vTh + (size_t)row * NSRC;
    float s = 0.f;
    for (int j = threadIdx.x; j < NSRC; j += 256) s += bf2f(ph[j]);
    #pragma unroll
    for (int off = 32; off > 0; off >>= 1) s += __shfl_down(s, off, 64);
    __shared__ float r4[4];
    if ((threadIdx.x & 63) == 0) r4[threadIdx.x >> 6] = s;
    __syncthreads();
    if (threadIdx.x == 0) vs[row] = r4[0] + r4[1] + r4[2] + r4[3];
}

// ---------------- pass B: dbuf; 2 i-frags/wave; P̃ = exp2(KQ^T)·rcs; O = P̃·V ----------------
// 1-D grid 512: id%8==bh%8; block covers 128 i (wave: 32), j-quarter loop
__global__ __launch_bounds__(256, 3) void pass_b(const u16* __restrict__ q,
    const u16* __restrict__ k, const u16* __restrict__ vTh,
    const float* __restrict__ rcs, u16* __restrict__ pvb, float* __restrict__ rs)
{
    int id = blockIdx.x;
    int slot = id >> 3;              // 0..63
    int bh = (id & 7) + 8 * (slot >> 5);
    int rem = slot & 31;
    int split = rem >> 3;            // 0..3
    int i0 = (rem & 7) * 128;        // 0..896
    int t = threadIdx.x, wave = t >> 6, lane = t & 63;
    const u16* qb = q + (size_t)bh * NSINK * HD;
    const u16* kb = k + (size_t)bh * NSRC * HD;
    const u16* vb = vTh + (size_t)bh * HD * NSRC;
    const float* rc = rcs + (size_t)bh * NSRC;

    __shared__ u16 Ks[2][64 * 64];
    __shared__ u16 Vs[2][64 * 64];
    __shared__ alignas(16) float RcsF[2][64];
#if !HAVE_PERMLANE
    __shared__ alignas(16) u16 pbuf[4][2][16 * 76];   // fallback transpose buffer
#endif

    short8 qf[2][2];   // [fi][kc]
    #pragma unroll
    for (int fi = 0; fi < 2; ++fi)
        #pragma unroll
        for (int kc = 0; kc < 2; ++kc)
            qf[fi][kc] = ldfrag(qb + (size_t)(i0 + wave * 32 + fi * 16) * HD + kc * 32, HD, lane);

    // constant ones B-fragment row 0 for the rowsum MFMA
    short8 ones8;
    #pragma unroll
    for (int i = 0; i < 8; ++i) ones8[i] = (short)0x3F80;
    short8 z = {};
    short8 b5 = ((lane & 15) == 0) ? ones8 : z;

    auto stage = [&](int buf, int jt) {
        int j0 = split * (NSRC / 4) + jt * 64;
        stage_tile<64>(Ks[buf], kb + (size_t)j0 * HD, HD, t);
        stage_tile<64>(Vs[buf], vb + j0, NSRC, t);
        if (t < 16) gld16((const u16*)(rc + j0) + t * 8, (u16*)RcsF[buf]);
    };

    f32x4 o[2][5] = {};
    stage(0, 0);
    __syncthreads();
    int cur = 0;
    for (int jt = 0; jt < 16; ++jt) {
        if (jt + 1 < 16) stage(cur ^ 1, jt + 1);   // prefetch overlaps compute
        // swapped QK^T: each K frag read once, feeds both i-frags
        f32x4 s[2][4] = {};
        #pragma unroll
        for (int kc = 0; kc < 2; ++kc)
            #pragma unroll
            for (int jf = 0; jf < 4; ++jf) {
                short8 kf = rdfrag(Ks[cur], jf * 16, kc * 4, lane);
                s[0][jf] = mfma16(kf, qf[0][kc], s[0][jf]);
                s[1][jf] = mfma16(kf, qf[1][kc], s[1][jf]);
            }
        // P̃ = exp2(S) * rcs[j]   (j = jf*16 + (lane>>4)*4 + r, contiguous in r)
        #pragma unroll
        for (int jf = 0; jf < 4; ++jf) {
            f32x4 rcv = *(const f32x4*)&RcsF[cur][jf * 16 + ((lane >> 4) << 2)];
            #pragma unroll
            for (int fi = 0; fi < 2; ++fi)
                #pragma unroll
                for (int r = 0; r < 4; ++r)
                    s[fi][jf][r] = fast_exp2(s[fi][jf][r]) * rcv[r];
        }
#if !HAVE_PERMLANE
        #pragma unroll
        for (int fi = 0; fi < 2; ++fi)
            #pragma unroll
            for (int jf = 0; jf < 4; ++jf) {
                uint2 w;
                w.x = pk_bf16(s[fi][jf][0], s[fi][jf][1]);
                w.y = pk_bf16(s[fi][jf][2], s[fi][jf][3]);
                *(uint2*)&pbuf[wave][fi][(size_t)(lane & 15) * 76 + jf * 16 + (lane >> 4) * 4] = w;
            }
#endif
        // PV: each V frag read once, feeds both i-frags; 5th = ones row (rowsum)
        #pragma unroll
        for (int jc = 0; jc < 2; ++jc) {
#if HAVE_PERMLANE
            short8 pa0 = pa_frag(s[0][2 * jc], s[0][2 * jc + 1]);
            short8 pa1 = pa_frag(s[1][2 * jc], s[1][2 * jc + 1]);
#else
            short8 pa0 = *(const short8*)&pbuf[wave][0][(size_t)(lane & 15) * 76 + jc * 32 + (lane >> 4) * 8];
            short8 pa1 = *(const short8*)&pbuf[wave][1][(size_t)(lane & 15) * 76 + jc * 32 + (lane >> 4) * 8];
#endif
            #pragma unroll
            for (int df = 0; df < 4; ++df) {
                short8 vf = rdfrag(Vs[cur], df * 16, jc * 4, lane);
                o[0][df] = mfma16(pa0, vf, o[0][df]);
                o[1][df] = mfma16(pa1, vf, o[1][df]);
            }
            o[0][4] = mfma16(pa0, b5, o[0][4]);
            o[1][4] = mfma16(pa1, b5, o[1][4]);
        }
        __syncthreads();   // drains prefetch vmcnt; guards buffer reuse
        cur ^= 1;
    }
    // rowsum = o[fi][4] col 0 (lanes with lane&15==0)
    if ((lane & 15) == 0) {
        #pragma unroll
        for (int fi = 0; fi < 2; ++fi)
            #pragma unroll
            for (int r = 0; r < 4; ++r)
                rs[((size_t)split * (BATCH * NH) + bh) * NSINK + i0 + wave * 32 + fi * 16 + (lane >> 4) * 4 + r] = o[fi][4][r];
    }
    int b = bh >> 3, h = bh & 7;
    u16* pvp = pvb + (size_t)split * BATCH * NSINK * DIM;
    #pragma unroll
    for (int fi = 0; fi < 2; ++fi)
        #pragma unroll
        for (int df = 0; df < 4; ++df)
            #pragma unroll
            for (int r = 0; r < 4; ++r) {
                int row = i0 + wave * 32 + fi * 16 + (lane >> 4) * 4 + r;
                pvp[((size_t)(b * NSINK + row)) * DIM + h * HD + df * 16 + (lane & 15)] = f2bf(o[fi][df][r]);
            }
}

// ---------------- finalize: a = (sum pv + eps*vsum)/(sum rs + Neps) -> bf16 ----------------
__global__ __launch_bounds__(256) void finalize_pv(const u16* __restrict__ pvb,
    const float* __restrict__ rs, const float* __restrict__ vs,
    u16* __restrict__ ab)
{
    const int M = BATCH * NSINK * DIM;
    const int R = BATCH * NH * NSINK;
    int idx = blockIdx.x * 256 + threadIdx.x;
    int m = idx >> 9, n = idx & 511;
    int b = m >> 10, i = m & 1023, h = n >> 6, d = n & 63;
    int bh = b * NH + h;
    float val = bf2f(pvb[idx]) + bf2f(pvb[idx + M]) + bf2f(pvb[idx + 2 * M])
              + bf2f(pvb[idx + 3 * M]) + EPS * vs[bh * HD + d];
    float rsv = rs[bh * NSINK + i] + rs[R + bh * NSINK + i]
              + rs[2 * R + bh * NSINK + i] + rs[3 * R + bh * NSINK + i]
              + (float)NSRC * EPS;
    ab[idx] = f2bf(val / rsv);
}

extern "C" void kernel_launch(void* const* d_in, const int* in_sizes, int n_in,
                              void* d_out, int out_size, void* d_ws, size_t ws_size,
                              hipStream_t stream) {
    (void)in_sizes; (void)n_in; (void)out_size;
    const float* sink    = (const float*)d_in[0];
    const float* source  = (const float*)d_in[1];
    const float* gamma_s = (const float*)d_in[2];
    const float* beta_s  = (const float*)d_in[3];
    const float* gamma_c = (const float*)d_in[4];
    const float* beta_c  = (const float*)d_in[5];
    const float* Wq      = (const float*)d_in[6];
    const float* bq      = (const float*)d_in[7];
    const float* Wkv     = (const float*)d_in[8];
    const float* bkv     = (const float*)d_in[9];
    const float* Wo      = (const float*)d_in[10];
    const float* bo      = (const float*)d_in[11];
    float* out = (float*)d_out;

    char* p = (char*)d_ws;
    auto carve = [&](size_t bytes) { char* r = p; p += (bytes + 255) & ~(size_t)255; return r; };
    u16* sh    = (u16*)carve(2048ull * 512 * 2);       // LN'd sink
    u16* ch    = (u16*)carve(8192ull * 512 * 2);       // LN'd source
    u16* wqT   = (u16*)carve(512ull * 512 * 2);
    u16* wkvT  = (u16*)carve(1024ull * 512 * 2);
    u16* woT   = (u16*)carve(512ull * 512 * 2);
    u16* qb    = (u16*)carve(16ull * 1024 * 64 * 2);
    u16* kb    = (u16*)carve(16ull * 4096 * 64 * 2);
    u16* vTh   = (u16*)carve(16ull * 64 * 4096 * 2);
    float* cs_part = (float*)carve(4ull * 16 * 4096 * 4);
    float* rcs     = (float*)carve(16ull * 4096 * 4);
    float* vs      = (float*)carve(1024ull * 4);
    float* rs      = (float*)carve(4ull * 16 * 1024 * 4);
    u16*   pvb     = (u16*)carve(4ull * 2048 * 512 * 2);
    u16*   ab      = (u16*)carve(2048ull * 512 * 2);
    if ((size_t)(p - (char*)d_ws) > ws_size) return;

    prep<<<BATCH * (NSINK + NSRC) + 2048, 256, 0, stream>>>(
        sink, source, gamma_s, beta_s, gamma_c, beta_c,
        Wq, Wkv, Wo, sh, ch, wqT, wkvT, woT);

    gemm1<1, 64, 64, 0><<<dim3(DIM / 64, BATCH * NSINK / 64), 256, 0, stream>>>(
        sh, wqT, bq, 512, nullptr, qb, nullptr);
    // KV: XCD-affine 1-D grid (64 m-tiles x 8 n-tiles)
    gemm1<2, 128, 128, 1><<<512, 256, 0, stream>>>(
        ch, wkvT, bkv, 512, nullptr, kb, vTh);

    pass_a<<<1024, 256, 0, stream>>>(qb, kb, cs_part);
    csred_vsum<<<256 + 1024, 256, 0, stream>>>(cs_part, vTh, rcs, vs);
    pass_b<<<512, 256, 0, stream>>>(qb, kb, vTh, rcs, pvb, rs);
    finalize_pv<<<4096, 256, 0, stream>>>(pvb, rs, vs, ab);

    gemm1<0, 64, 64, 0><<<dim3(DIM / 64, BATCH * NSINK / 64), 256, 0, stream>>>(
        ab, woT, bo, 512, out, nullptr, nullptr);
}

// Round 15
// 98.448 us; speedup vs baseline: 1.0823x; 1.0823x over previous
//
#include <hip/hip_runtime.h>
#include <hip/hip_bf16.h>
#include <math.h>

#define EPS 1e-6f
#define NSINK 1024
#define NSRC 4096
#define DIM 512
#define NH 8
#define HD 64
#define BATCH 2
// fold (d^-0.5 = 1/8) * log2(e) into q so sim exp is a single exp2
#define QSCALE 0.18033688011112042f

#if __has_builtin(__builtin_amdgcn_permlane32_swap) && __has_builtin(__builtin_amdgcn_permlane16_swap)
#define HAVE_PERMLANE 1
#else
#define HAVE_PERMLANE 0
#endif

typedef unsigned short u16;
typedef __attribute__((ext_vector_type(8))) short short8;
typedef __attribute__((ext_vector_type(4))) float f32x4;

__device__ inline float fast_exp2(float x) {
#if __has_builtin(__builtin_amdgcn_exp2f)
    return __builtin_amdgcn_exp2f(x);
#else
    return exp2f(x);
#endif
}
__device__ inline float fast_rcp(float x) {
#if __has_builtin(__builtin_amdgcn_rcpf)
    return __builtin_amdgcn_rcpf(x);
#else
    return 1.0f / x;
#endif
}
__device__ inline u16 f2bf(float x) {
    union { float f; unsigned u; } v; v.f = x;
    unsigned r = v.u + 0x7fffu + ((v.u >> 16) & 1u);
    return (u16)(r >> 16);
}
__device__ inline float bf2f(u16 h) {
    union { unsigned u; float f; } v; v.u = ((unsigned)h) << 16;
    return v.f;
}
// pack 2 f32 -> 2 bf16 (RTNE) in one u32; lowers to v_cvt_pk_bf16_f32
__device__ inline unsigned pk_bf16(float a, float b) {
    union { __hip_bfloat162 h; unsigned u; } v;
    v.h = __float22bfloat162_rn(make_float2(a, b));
    return v.u;
}
__device__ inline f32x4 mfma16(short8 a, short8 b, f32x4 c) {
    return __builtin_amdgcn_mfma_f32_16x16x32_bf16(a, b, c, 0, 0, 0);
}
// direct-from-global fragment loader
__device__ inline short8 ldfrag(const u16* base, int stride, int lane) {
    return *(const short8*)(base + (size_t)(lane & 15) * stride + ((lane >> 4) << 3));
}

// async global->LDS, 16B per lane
__device__ inline void gld16(const u16* g, u16* l) {
    __builtin_amdgcn_global_load_lds(
        (const __attribute__((address_space(1))) unsigned*)g,
        (__attribute__((address_space(3))) unsigned*)l, 16, 0, 0);
}

// stage a [TM][64] bf16 tile from gsrc (row-major, stride K);
// LDS linear dest; global source inverse-swizzled (c ^= m&7).
template<int TM>
__device__ inline void stage_tile(u16* lds, const u16* gsrc, int K, int t) {
    #pragma unroll
    for (int it = 0; it < TM / 32; ++it) {
        int m = it * 32 + (t >> 3);
        int c = (t & 7) ^ (m & 7);
        gld16(gsrc + (size_t)m * K + c * 8,
              lds + it * 2048 + (t >> 6) * 512);
    }
}
// swizzled fragment read
__device__ inline short8 rdfrag(const u16* tile, int fbase, int cbase, int lane) {
    int m = fbase + (lane & 15);
    int c = (cbase + (lane >> 4)) ^ (m & 7);
    return *(const short8*)(tile + (size_t)m * 64 + c * 8);
}

#if HAVE_PERMLANE
// Build the PV A-fragment in-register from swapped-QK scores (already scaled).
__device__ inline short8 pa_frag(const f32x4 sA, const f32x4 sB) {
    unsigned A0 = pk_bf16(sA[0], sA[1]);
    unsigned A1 = pk_bf16(sA[2], sA[3]);
    unsigned B0 = pk_bf16(sB[0], sB[1]);
    unsigned B1 = pk_bf16(sB[2], sB[3]);
    auto c0 = __builtin_amdgcn_permlane32_swap(A0, B0, false, false);
    auto c1 = __builtin_amdgcn_permlane32_swap(A1, B1, false, false);
    auto d0 = __builtin_amdgcn_permlane16_swap(c0[0], c0[1], false, false);
    auto d1 = __builtin_amdgcn_permlane16_swap(c1[0], c1[1], false, false);
    union { unsigned u[4]; short8 s8; } r;
    r.u[0] = d0[0]; r.u[1] = d1[0]; r.u[2] = d0[1]; r.u[3] = d1[1];
    return r.s8;
}
#endif

// ---------------- prep: fused LayerNorm (both inputs) + weight transposes ----------------
__global__ __launch_bounds__(256) void prep(
    const float* __restrict__ sink, const float* __restrict__ source,
    const float* __restrict__ gs, const float* __restrict__ bs,
    const float* __restrict__ gc, const float* __restrict__ bc,
    const float* __restrict__ Wq, const float* __restrict__ Wkv,
    const float* __restrict__ Wo,
    u16* __restrict__ sh, u16* __restrict__ ch,
    u16* __restrict__ wqT, u16* __restrict__ wkvT, u16* __restrict__ woT)
{
    int row = blockIdx.x;
    int t = threadIdx.x;
    if (row >= BATCH * (NSINK + NSRC)) {   // weight transpose blocks
        int n = row - BATCH * (NSINK + NSRC);
        const float* W; u16* T; int N; int nn;
        if (n < 512)       { W = Wq;  T = wqT;  N = 512;  nn = n; }
        else if (n < 1536) { W = Wkv; T = wkvT; N = 1024; nn = n - 512; }
        else               { W = Wo;  T = woT;  N = 512;  nn = n - 1536; }
        for (int k = t; k < 512; k += 256)
            T[(size_t)nn * 512 + k] = f2bf(W[(size_t)k * N + nn]);
        return;
    }
    const float* xr; const float* g; const float* be; u16* y;
    if (row < BATCH * NSINK) {
        xr = sink + (size_t)row * DIM; g = gs; be = bs; y = sh + (size_t)row * DIM;
    } else {
        int rr = row - BATCH * NSINK;
        xr = source + (size_t)rr * DIM; g = gc; be = bc; y = ch + (size_t)rr * DIM;
    }
    float v0 = xr[t], v1 = xr[t + 256];
    float s = v0 + v1, sq = v0 * v0 + v1 * v1;
    #pragma unroll
    for (int off = 32; off > 0; off >>= 1) {
        s  += __shfl_down(s, off, 64);
        sq += __shfl_down(sq, off, 64);
    }
    __shared__ float rsm[4], rq[4];
    int wave = t >> 6;
    if ((t & 63) == 0) { rsm[wave] = s; rq[wave] = sq; }
    __syncthreads();
    s  = rsm[0] + rsm[1] + rsm[2] + rsm[3];
    sq = rq[0] + rq[1] + rq[2] + rq[3];
    float mu = s * (1.0f / DIM);
    float var = sq * (1.0f / DIM) - mu * mu;
    float a = var + EPS;
    float r = rsqrtf(a);
    r = r * (1.5f - 0.5f * a * r * r);
    y[t]       = f2bf((v0 - mu) * r * g[t] + be[t]);
    y[t + 256] = f2bf((v1 - mu) * r * g[t + 256] + be[t + 256]);
}

// ---------------- 1-term 2-phase LDS-dbuf MFMA GEMM body ----------------
// MODE 0: C fp32 row-major. MODE 1: q bf16 [bh][i][d] * QSCALE.
// MODE 2: n<512 -> k bf16 [bh][j][d]; n>=512 -> vT bf16 [bh*64+d][j] via LDS transpose.
template<int MODE, int TM, int TN>
__device__ inline void gemm_body(u16* smem, int m0, int n0,
    const u16* __restrict__ A, const u16* __restrict__ BT,
    const float* __restrict__ bias, int K,
    float* __restrict__ cf, u16* __restrict__ o1, u16* __restrict__ o2, int t)
{
    constexpr int FM = TM / 32, FN = TN / 32;
    u16* Asb[2] = { smem, smem + TM * 64 };
    u16* Bsb[2] = { smem + 2 * TM * 64, smem + 2 * TM * 64 + TN * 64 };
    int wave = t >> 6, lane = t & 63;
    int wr = wave >> 1, wc = wave & 1;

    f32x4 acc[FM][FN] = {};
    stage_tile<TM>(Asb[0], A + (size_t)m0 * K, K, t);
    stage_tile<TN>(Bsb[0], BT + (size_t)n0 * K, K, t);
    __syncthreads();
    int nt = K >> 6;
    int cur = 0;
    for (int kt = 0; kt < nt; ++kt) {
        if (kt + 1 < nt) {
            stage_tile<TM>(Asb[cur ^ 1], A + (size_t)m0 * K + (kt + 1) * 64, K, t);
            stage_tile<TN>(Bsb[cur ^ 1], BT + (size_t)n0 * K + (kt + 1) * 64, K, t);
        }
        #pragma unroll
        for (int kk = 0; kk < 2; ++kk) {
            short8 af[FM], bf[FN];
            #pragma unroll
            for (int f = 0; f < FM; ++f)
                af[f] = rdfrag(Asb[cur], wr * (TM / 2) + f * 16, kk * 4, lane);
            #pragma unroll
            for (int f = 0; f < FN; ++f)
                bf[f] = rdfrag(Bsb[cur], wc * (TN / 2) + f * 16, kk * 4, lane);
            #pragma unroll
            for (int i = 0; i < FM; ++i)
                #pragma unroll
                for (int j = 0; j < FN; ++j)
                    acc[i][j] = mfma16(af[i], bf[j], acc[i][j]);
        }
        __syncthreads();
        cur ^= 1;
    }

    if (MODE == 2 && n0 >= DIM) {
        // v-half: LDS-transpose epilogue -> coalesced vT writes
        u16* tb = smem;   // [128][140] u16 = 35840 B, fits (K-loop done)
        #pragma unroll
        for (int i = 0; i < FM; ++i)
            #pragma unroll
            for (int j = 0; j < FN; ++j) {
                int nl = wc * (TN / 2) + j * 16 + (lane & 15);
                int ml = wr * (TM / 2) + i * 16 + ((lane >> 4) << 2);
                float bia = bias[n0 + nl];
                union { u16 h[4]; uint2 v; } pk;
                #pragma unroll
                for (int r = 0; r < 4; ++r) pk.h[r] = f2bf(acc[i][j][r] + bia);
                *(uint2*)&tb[(size_t)nl * 140 + ml] = pk.v;
            }
        __syncthreads();
        int rowl = t >> 1, seg = t & 1;
        int nn = n0 + rowl - DIM;
        int h = nn >> 6, d = nn & 63;
        int b = m0 >> 12, jj0 = m0 & 4095;
        u16* dst = o2 + ((size_t)(b * NH + h) * HD + d) * NSRC + jj0 + seg * 64;
        const u16* sp = tb + (size_t)rowl * 140 + seg * 64;
        // copy 64 u16 (128 B) per thread: 16 x uint2 (4 u16 each), stride 4
        #pragma unroll
        for (int c = 0; c < 16; ++c)
            *(uint2*)(dst + c * 4) = *(const uint2*)(sp + c * 4);
        return;
    }

    #pragma unroll
    for (int i = 0; i < FM; ++i)
        #pragma unroll
        for (int j = 0; j < FN; ++j)
            #pragma unroll
            for (int r = 0; r < 4; ++r) {
                int m = m0 + wr * (TM / 2) + i * 16 + (lane >> 4) * 4 + r;
                int n = n0 + wc * (TN / 2) + j * 16 + (lane & 15);
                float v = acc[i][j][r] + bias[n];
                if (MODE == 0) {
                    cf[(size_t)m * DIM + n] = v;
                } else if (MODE == 1) {
                    int b = m >> 10, ii = m & 1023;
                    int h = n >> 6, d = n & 63;
                    o1[((size_t)(b * NH + h) * NSINK + ii) * HD + d] = f2bf(v * QSCALE);
                } else {  // MODE 2, k half (n < DIM)
                    int b = m >> 12, jj = m & 4095;
                    int h = n >> 6, d = n & 63;
                    o1[((size_t)(b * NH + h) * NSRC + jj) * HD + d] = f2bf(v);
                }
            }
}

// Combined Q + KV projection launch: blocks 0..511 = KV (128x128, XCD-affine),
// blocks 512..767 = Q (64x64).
__global__ __launch_bounds__(256) void gemm_qkv(
    const u16* __restrict__ sh, const u16* __restrict__ ch,
    const u16* __restrict__ wqT, const u16* __restrict__ wkvT,
    const float* __restrict__ bq, const float* __restrict__ bkv,
    u16* __restrict__ qb, u16* __restrict__ kb, u16* __restrict__ vTh)
{
    __shared__ u16 smem[32768];   // 64 KB
    int id = blockIdx.x, t = threadIdx.x;
    if (id < 512) {
        int slot = id >> 3;             // XCD-affine: id&7 = XCD slab
        int m0 = ((id & 7) * 8 + (slot & 7)) * 128;
        int n0 = (slot >> 3) * 128;
        gemm_body<2, 128, 128>(smem, m0, n0, ch, wkvT, bkv, 512, nullptr, kb, vTh, t);
    } else {
        int q = id - 512;               // 256 blocks: 32 m-tiles x 8 n-tiles
        int m0 = (q >> 3) * 64;
        int n0 = (q & 7) * 64;
        gemm_body<1, 64, 64>(smem, m0, n0, sh, wqT, bq, 512, nullptr, qb, nullptr, t);
    }
}

// out-projection: C = ab @ woT^T + bo
__global__ __launch_bounds__(256) void gemm_o(
    const u16* __restrict__ ab, const u16* __restrict__ woT,
    const float* __restrict__ bo, float* __restrict__ out)
{
    __shared__ u16 smem[16384];   // 32 KB
    gemm_body<0, 64, 64>(smem, blockIdx.y * 64, blockIdx.x * 64,
                         ab, woT, bo, 512, out, nullptr, nullptr, threadIdx.x);
}

// ---------------- pass A: colsum_part[ic][bh][j] = sum_{i chunk} exp2(q.k) ----------------
__global__ __launch_bounds__(256, 4) void pass_a(const u16* __restrict__ q,
    const u16* __restrict__ k, float* __restrict__ part)
{
    int id = blockIdx.x;
    int slot = id >> 3;
    int bh = (id & 7) + 8 * (slot >> 6);
    int rem = slot & 63;
    int ic = rem >> 4;
    int t = threadIdx.x, wave = t >> 6, lane = t & 63;
    int j0 = (rem & 15) * 256 + wave * 64;
    const u16* qb = q + (size_t)bh * NSINK * HD;
    const u16* kb = k + (size_t)bh * NSRC * HD;

    __shared__ u16 Qs[2][64 * 64];

    short8 kf[4][2];
    #pragma unroll
    for (int jf = 0; jf < 4; ++jf)
        #pragma unroll
        for (int kc = 0; kc < 2; ++kc)
            kf[jf][kc] = ldfrag(kb + (size_t)(j0 + jf * 16) * HD + kc * 32, HD, lane);

    float csum[4] = {};
    stage_tile<64>(Qs[0], qb + (size_t)(ic * 256) * HD, HD, t);
    __syncthreads();
    int cur = 0;
    for (int ii = 0; ii < 4; ++ii) {
        if (ii + 1 < 4)
            stage_tile<64>(Qs[cur ^ 1], qb + (size_t)(ic * 256 + (ii + 1) * 64) * HD, HD, t);
        #pragma unroll
        for (int f = 0; f < 4; ++f) {
            short8 q0 = rdfrag(Qs[cur], f * 16, 0, lane);
            short8 q1 = rdfrag(Qs[cur], f * 16, 4, lane);
            f32x4 s[4] = {};
            #pragma unroll
            for (int jf = 0; jf < 4; ++jf) s[jf] = mfma16(q0, kf[jf][0], s[jf]);
            #pragma unroll
            for (int jf = 0; jf < 4; ++jf) s[jf] = mfma16(q1, kf[jf][1], s[jf]);
            #pragma unroll
            for (int jf = 0; jf < 4; ++jf)
                csum[jf] += fast_exp2(s[jf][0]) + fast_exp2(s[jf][1])
                          + fast_exp2(s[jf][2]) + fast_exp2(s[jf][3]);
        }
        __syncthreads();   // drains prefetch vmcnt; guards buffer reuse
        cur ^= 1;
    }
    #pragma unroll
    for (int jf = 0; jf < 4; ++jf) {
        csum[jf] += __shfl_xor(csum[jf], 16, 64);
        csum[jf] += __shfl_xor(csum[jf], 32, 64);
    }
    if (lane < 16)
        #pragma unroll
        for (int jf = 0; jf < 4; ++jf)
            part[((size_t)ic * BATCH * NH + bh) * NSRC + j0 + jf * 16 + lane] = csum[jf];
}

// ---------------- csred_vsum: rcs = 1/sum(parts) (blocks 0..255); vs = sum_j v (blocks 256..1279) ----------------
__global__ __launch_bounds__(256) void csred_vsum(const float* __restrict__ part,
    const u16* __restrict__ vTh, float* __restrict__ rcs, float* __restrict__ vs)
{
    int blk = blockIdx.x;
    if (blk < 256) {
        int x = blk * 256 + threadIdx.x;   // 16*4096 total
        const int S = BATCH * NH * NSRC;
        float cs = part[x] + part[x + S] + part[x + 2 * S] + part[x + 3 * S];
        rcs[x] = fast_rcp(cs);
        return;
    }
    int row = blk - 256;                   // 0..1023 = bh*64+d
    const u16* ph = vTh + (size_t)row * NSRC;
    float s = 0.f;
    for (int j = threadIdx.x; j < NSRC; j += 256) s += bf2f(ph[j]);
    #pragma unroll
    for (int off = 32; off > 0; off >>= 1) s += __shfl_down(s, off, 64);
    __shared__ float r4[4];
    if ((threadIdx.x & 63) == 0) r4[threadIdx.x >> 6] = s;
    __syncthreads();
    if (threadIdx.x == 0) vs[row] = r4[0] + r4[1] + r4[2] + r4[3];
}

// ---------------- pass B: dbuf; 2 i-frags/wave; P̃ = exp2(KQ^T)·rcs; O = P̃·V ----------------
// 1-D grid 512: id%8==bh%8; block covers 128 i (wave: 32), j-quarter loop
__global__ __launch_bounds__(256, 3) void pass_b(const u16* __restrict__ q,
    const u16* __restrict__ k, const u16* __restrict__ vTh,
    const float* __restrict__ rcs, u16* __restrict__ pvb, float* __restrict__ rs)
{
    int id = blockIdx.x;
    int slot = id >> 3;              // 0..63
    int bh = (id & 7) + 8 * (slot >> 5);
    int rem = slot & 31;
    int split = rem >> 3;            // 0..3
    int i0 = (rem & 7) * 128;        // 0..896
    int t = threadIdx.x, wave = t >> 6, lane = t & 63;
    const u16* qb = q + (size_t)bh * NSINK * HD;
    const u16* kb = k + (size_t)bh * NSRC * HD;
    const u16* vb = vTh + (size_t)bh * HD * NSRC;
    const float* rc = rcs + (size_t)bh * NSRC;

    __shared__ u16 Ks[2][64 * 64];
    __shared__ u16 Vs[2][64 * 64];
    __shared__ alignas(16) float RcsF[2][64];
#if !HAVE_PERMLANE
    __shared__ alignas(16) u16 pbuf[4][2][16 * 76];   // fallback transpose buffer
#endif

    short8 qf[2][2];   // [fi][kc]
    #pragma unroll
    for (int fi = 0; fi < 2; ++fi)
        #pragma unroll
        for (int kc = 0; kc < 2; ++kc)
            qf[fi][kc] = ldfrag(qb + (size_t)(i0 + wave * 32 + fi * 16) * HD + kc * 32, HD, lane);

    // constant ones B-fragment row 0 for the rowsum MFMA
    short8 ones8;
    #pragma unroll
    for (int i = 0; i < 8; ++i) ones8[i] = (short)0x3F80;
    short8 z = {};
    short8 b5 = ((lane & 15) == 0) ? ones8 : z;

    auto stage = [&](int buf, int jt) {
        int j0 = split * (NSRC / 4) + jt * 64;
        stage_tile<64>(Ks[buf], kb + (size_t)j0 * HD, HD, t);
        stage_tile<64>(Vs[buf], vb + j0, NSRC, t);
        if (t < 16) gld16((const u16*)(rc + j0) + t * 8, (u16*)RcsF[buf]);
    };

    f32x4 o[2][5] = {};
    stage(0, 0);
    __syncthreads();
    int cur = 0;
    for (int jt = 0; jt < 16; ++jt) {
        if (jt + 1 < 16) stage(cur ^ 1, jt + 1);   // prefetch overlaps compute
        // swapped QK^T: each K frag read once, feeds both i-frags
        f32x4 s[2][4] = {};
        #pragma unroll
        for (int kc = 0; kc < 2; ++kc)
            #pragma unroll
            for (int jf = 0; jf < 4; ++jf) {
                short8 kf = rdfrag(Ks[cur], jf * 16, kc * 4, lane);
                s[0][jf] = mfma16(kf, qf[0][kc], s[0][jf]);
                s[1][jf] = mfma16(kf, qf[1][kc], s[1][jf]);
            }
        // P̃ = exp2(S) * rcs[j]   (j = jf*16 + (lane>>4)*4 + r, contiguous in r)
        #pragma unroll
        for (int jf = 0; jf < 4; ++jf) {
            f32x4 rcv = *(const f32x4*)&RcsF[cur][jf * 16 + ((lane >> 4) << 2)];
            #pragma unroll
            for (int fi = 0; fi < 2; ++fi)
                #pragma unroll
                for (int r = 0; r < 4; ++r)
                    s[fi][jf][r] = fast_exp2(s[fi][jf][r]) * rcv[r];
        }
#if !HAVE_PERMLANE
        #pragma unroll
        for (int fi = 0; fi < 2; ++fi)
            #pragma unroll
            for (int jf = 0; jf < 4; ++jf) {
                uint2 w;
                w.x = pk_bf16(s[fi][jf][0], s[fi][jf][1]);
                w.y = pk_bf16(s[fi][jf][2], s[fi][jf][3]);
                *(uint2*)&pbuf[wave][fi][(size_t)(lane & 15) * 76 + jf * 16 + (lane >> 4) * 4] = w;
            }
#endif
        // PV: each V frag read once, feeds both i-frags; 5th = ones row (rowsum)
        #pragma unroll
        for (int jc = 0; jc < 2; ++jc) {
#if HAVE_PERMLANE
            short8 pa0 = pa_frag(s[0][2 * jc], s[0][2 * jc + 1]);
            short8 pa1 = pa_frag(s[1][2 * jc], s[1][2 * jc + 1]);
#else
            short8 pa0 = *(const short8*)&pbuf[wave][0][(size_t)(lane & 15) * 76 + jc * 32 + (lane >> 4) * 8];
            short8 pa1 = *(const short8*)&pbuf[wave][1][(size_t)(lane & 15) * 76 + jc * 32 + (lane >> 4) * 8];
#endif
            #pragma unroll
            for (int df = 0; df < 4; ++df) {
                short8 vf = rdfrag(Vs[cur], df * 16, jc * 4, lane);
                o[0][df] = mfma16(pa0, vf, o[0][df]);
                o[1][df] = mfma16(pa1, vf, o[1][df]);
            }
            o[0][4] = mfma16(pa0, b5, o[0][4]);
            o[1][4] = mfma16(pa1, b5, o[1][4]);
        }
        __syncthreads();   // drains prefetch vmcnt; guards buffer reuse
        cur ^= 1;
    }
    // rowsum = o[fi][4] col 0 (lanes with lane&15==0)
    if ((lane & 15) == 0) {
        #pragma unroll
        for (int fi = 0; fi < 2; ++fi)
            #pragma unroll
            for (int r = 0; r < 4; ++r)
                rs[((size_t)split * (BATCH * NH) + bh) * NSINK + i0 + wave * 32 + fi * 16 + (lane >> 4) * 4 + r] = o[fi][4][r];
    }
    int b = bh >> 3, h = bh & 7;
    u16* pvp = pvb + (size_t)split * BATCH * NSINK * DIM;
    #pragma unroll
    for (int fi = 0; fi < 2; ++fi)
        #pragma unroll
        for (int df = 0; df < 4; ++df)
            #pragma unroll
            for (int r = 0; r < 4; ++r) {
                int row = i0 + wave * 32 + fi * 16 + (lane >> 4) * 4 + r;
                pvp[((size_t)(b * NSINK + row)) * DIM + h * HD + df * 16 + (lane & 15)] = f2bf(o[fi][df][r]);
            }
}

// ---------------- finalize: a = (sum pv + eps*vsum)/(sum rs + Neps) -> bf16 ----------------
__global__ __launch_bounds__(256) void finalize_pv(const u16* __restrict__ pvb,
    const float* __restrict__ rs, const float* __restrict__ vs,
    u16* __restrict__ ab)
{
    const int M = BATCH * NSINK * DIM;
    const int R = BATCH * NH * NSINK;
    int idx = blockIdx.x * 256 + threadIdx.x;
    int m = idx >> 9, n = idx & 511;
    int b = m >> 10, i = m & 1023, h = n >> 6, d = n & 63;
    int bh = b * NH + h;
    float val = bf2f(pvb[idx]) + bf2f(pvb[idx + M]) + bf2f(pvb[idx + 2 * M])
              + bf2f(pvb[idx + 3 * M]) + EPS * vs[bh * HD + d];
    float rsv = rs[bh * NSINK + i] + rs[R + bh * NSINK + i]
              + rs[2 * R + bh * NSINK + i] + rs[3 * R + bh * NSINK + i]
              + (float)NSRC * EPS;
    ab[idx] = f2bf(val / rsv);
}

extern "C" void kernel_launch(void* const* d_in, const int* in_sizes, int n_in,
                              void* d_out, int out_size, void* d_ws, size_t ws_size,
                              hipStream_t stream) {
    (void)in_sizes; (void)n_in; (void)out_size;
    const float* sink    = (const float*)d_in[0];
    const float* source  = (const float*)d_in[1];
    const float* gamma_s = (const float*)d_in[2];
    const float* beta_s  = (const float*)d_in[3];
    const float* gamma_c = (const float*)d_in[4];
    const float* beta_c  = (const float*)d_in[5];
    const float* Wq      = (const float*)d_in[6];
    const float* bq      = (const float*)d_in[7];
    const float* Wkv     = (const float*)d_in[8];
    const float* bkv     = (const float*)d_in[9];
    const float* Wo      = (const float*)d_in[10];
    const float* bo      = (const float*)d_in[11];
    float* out = (float*)d_out;

    char* p = (char*)d_ws;
    auto carve = [&](size_t bytes) { char* r = p; p += (bytes + 255) & ~(size_t)255; return r; };
    u16* sh    = (u16*)carve(2048ull * 512 * 2);       // LN'd sink
    u16* ch    = (u16*)carve(8192ull * 512 * 2);       // LN'd source
    u16* wqT   = (u16*)carve(512ull * 512 * 2);
    u16* wkvT  = (u16*)carve(1024ull * 512 * 2);
    u16* woT   = (u16*)carve(512ull * 512 * 2);
    u16* qb    = (u16*)carve(16ull * 1024 * 64 * 2);
    u16* kb    = (u16*)carve(16ull * 4096 * 64 * 2);
    u16* vTh   = (u16*)carve(16ull * 64 * 4096 * 2);
    float* cs_part = (float*)carve(4ull * 16 * 4096 * 4);
    float* rcs     = (float*)carve(16ull * 4096 * 4);
    float* vs      = (float*)carve(1024ull * 4);
    float* rs      = (float*)carve(4ull * 16 * 1024 * 4);
    u16*   pvb     = (u16*)carve(4ull * 2048 * 512 * 2);
    u16*   ab      = (u16*)carve(2048ull * 512 * 2);
    if ((size_t)(p - (char*)d_ws) > ws_size) return;

    prep<<<BATCH * (NSINK + NSRC) + 2048, 256, 0, stream>>>(
        sink, source, gamma_s, beta_s, gamma_c, beta_c,
        Wq, Wkv, Wo, sh, ch, wqT, wkvT, woT);

    // Q + KV projections in one launch (768 blocks)
    gemm_qkv<<<768, 256, 0, stream>>>(sh, ch, wqT, wkvT, bq, bkv, qb, kb, vTh);

    pass_a<<<1024, 256, 0, stream>>>(qb, kb, cs_part);
    csred_vsum<<<256 + 1024, 256, 0, stream>>>(cs_part, vTh, rcs, vs);
    pass_b<<<512, 256, 0, stream>>>(qb, kb, vTh, rcs, pvb, rs);
    finalize_pv<<<4096, 256, 0, stream>>>(pvb, rs, vs, ab);

    gemm_o<<<dim3(DIM / 64, BATCH * NSINK / 64), 256, 0, stream>>>(ab, woT, bo, out);
}